// Round 14
// baseline (195.973 us; speedup 1.0000x reference)
//
#include <hip/hip_runtime.h>
#include <math.h>

#define NB 2
#define NC 96
#define NN 8000
#define DI 192
#define DS 16
#define DTRK 6
#define KCH 320
#define LCH 25

// ws layout (element offsets, 4B each) — all dedicated, no aliasing
#define OFF_RP   0                              // 8*8000 int partial ranks
#define OFF_XN   64000
#define OFF_XC   (OFF_XN + NB*NN*NC)
#define OFF_Z    (OFF_XC + NB*NN*DI)
#define OFF_XCV  (OFF_Z  + NB*NN*DI)
#define OFF_DT   (OFF_XCV + NB*NN*DI)
#define OFF_BM   (OFF_DT + NB*NN*DI)
#define OFF_CM   (OFF_BM + NB*NN*DS)
#define OFF_CA   (OFF_CM + NB*NN*DS)
#define OFF_CB   (OFF_CA + NB*KCH*DI*DS)
#define OFF_HS   (OFF_CB + NB*KCH*DI*DS)
#define OFF_Y    (OFF_HS + NB*KCH*DI*DS)
#define OFF_YP   (OFF_Y  + NB*NN*DI)

// ---------------- A: O(N^2) stable rank partials; keys computed in-block ----------------
__global__ void k_rank(const float* __restrict__ pv, int* __restrict__ rp) {
    __shared__ float kj[1000];
    int t = threadIdx.x;
    float p0 = pv[0], p1 = pv[1], p2 = pv[2];
    int j0 = blockIdx.y * 1000;
    for (int j = t; j < 1000; j += 256) {
        int idx = j0 + j;
        int zz = idx / 400, rem = idx % 400, yy = rem / 20, xx = rem % 20;
        kj[j] = (float)zz * p0 + (float)yy * p1 + (float)xx * p2;
    }
    __syncthreads();
    int i = blockIdx.x * 256 + t;
    if (i >= NN) return;
    {
        int zz = i / 400, rem = i % 400, yy = rem / 20, xx = rem % 20;
        float ki = (float)zz * p0 + (float)yy * p1 + (float)xx * p2;
        int cnt = 0;
        #pragma unroll 4
        for (int j = 0; j < 1000; ++j) {
            float kv = kj[j];
            int jj = j0 + j;
            cnt += (kv < ki || (kv == ki && jj < i)) ? 1 : 0;
        }
        rp[blockIdx.y * 8000 + i] = cnt;
    }
}

// ------- B1: LayerNorm + row-scatter to sorted xn (B,N,96) -------
__launch_bounds__(256)
__global__ void k_ln(const float* __restrict__ x, const float* __restrict__ nw,
                     const float* __restrict__ nbp, const int* __restrict__ rp,
                     float* __restrict__ xn) {
    __shared__ float xt[64][100];
    __shared__ int rk[64];
    __shared__ float nwb[NC], nbb[NC];
    int b = blockIdx.y, n0 = blockIdx.x * 64, t = threadIdx.x;
    int lane = t & 63, w = t >> 6;
    if (t < 64) {
        int s = 0;
        #pragma unroll
        for (int c = 0; c < 8; ++c) s += rp[c * 8000 + n0 + t];
        rk[t] = s;
    } else if (t >= 64 && t < 160) { int c = t - 64; nwb[c] = nw[c]; nbb[c] = nbp[c]; }
    for (int idx = t; idx < NC * 64; idx += 256) {
        int c = idx >> 6, p = idx & 63;
        xt[p][c] = x[((size_t)b * NC + c) * NN + n0 + p];
    }
    __syncthreads();
    // per-lane LN (4 waves redundant)
    float xr[96];
    float s = 0.f, sq = 0.f;
    #pragma unroll
    for (int c4 = 0; c4 < 24; ++c4) {
        float4 v = *(const float4*)&xt[lane][c4 * 4];
        xr[c4*4+0] = v.x; xr[c4*4+1] = v.y; xr[c4*4+2] = v.z; xr[c4*4+3] = v.w;
        s += v.x + v.y + v.z + v.w;
        sq += v.x*v.x + v.y*v.y + v.z*v.z + v.w*v.w;
    }
    float mu = s * (1.f / 96.f);
    float var = sq * (1.f / 96.f) - mu * mu;
    float rs = rsqrtf(var + 1e-5f);
    #pragma unroll
    for (int c = 0; c < 96; ++c) xr[c] = (xr[c] - mu) * rs * nwb[c] + nbb[c];
    __syncthreads();
    if (w == 0) {
        #pragma unroll
        for (int c = 0; c < 96; ++c) xt[lane][c] = xr[c];
    }
    __syncthreads();
    for (int idx = t; idx < 64 * 24; idx += 256) {
        int p = idx / 24, c4 = idx % 24;
        *(float4*)&xn[((size_t)b * NN + rk[p]) * NC + c4 * 4] = *(const float4*)&xt[p][c4 * 4];
    }
}

// ------- B2: in_proj GEMM, row-major LDS tiles, 4pos x 3out threads -------
__launch_bounds__(256, 3)
__global__ void k_inproj(const float* __restrict__ xn, const float* __restrict__ win,
                         float* __restrict__ xcout, float* __restrict__ zout) {
    __shared__ float wsm[48][100];
    __shared__ float xs[64][100];
    int b = blockIdx.z, g = blockIdx.y, n0 = blockIdx.x * 64, t = threadIdx.x;

    for (int i = t; i < 48 * 24; i += 256) {
        int r = i / 24, c4 = i % 24;
        *(float4*)&wsm[r][c4 * 4] = *(const float4*)(win + (size_t)(g * 48 + r) * NC + c4 * 4);
    }
    for (int i = t; i < 64 * 24; i += 256) {
        int p = i / 24, c4 = i % 24;
        *(float4*)&xs[p][c4 * 4] = *(const float4*)(xn + ((size_t)b * NN + n0 + p) * NC + c4 * 4);
    }
    __syncthreads();

    int oi = t & 15, pi = t >> 4;
    float acc[3][4];
    #pragma unroll
    for (int j = 0; j < 3; ++j)
        #pragma unroll
        for (int pp = 0; pp < 4; ++pp) acc[j][pp] = 0.f;

    for (int c4 = 0; c4 < 24; ++c4) {
        float4 b0 = *(const float4*)&wsm[oi * 3 + 0][c4 * 4];
        float4 b1 = *(const float4*)&wsm[oi * 3 + 1][c4 * 4];
        float4 b2 = *(const float4*)&wsm[oi * 3 + 2][c4 * 4];
        #pragma unroll
        for (int pp = 0; pp < 4; ++pp) {
            float4 a = *(const float4*)&xs[pi * 4 + pp][c4 * 4];
            acc[0][pp] = fmaf(a.x, b0.x, fmaf(a.y, b0.y, fmaf(a.z, b0.z, fmaf(a.w, b0.w, acc[0][pp]))));
            acc[1][pp] = fmaf(a.x, b1.x, fmaf(a.y, b1.y, fmaf(a.z, b1.z, fmaf(a.w, b1.w, acc[1][pp]))));
            acc[2][pp] = fmaf(a.x, b2.x, fmaf(a.y, b2.y, fmaf(a.z, b2.z, fmaf(a.w, b2.w, acc[2][pp]))));
        }
    }
    __syncthreads();
    #pragma unroll
    for (int j = 0; j < 3; ++j)
        #pragma unroll
        for (int pp = 0; pp < 4; ++pp) xs[pi * 4 + pp][oi * 3 + j] = acc[j][pp];
    __syncthreads();

    float* outp = (g < 4) ? xcout : zout;
    int co = (g & 3) * 48;
    for (int i = t; i < 64 * 12; i += 256) {
        int p = i / 12, o4 = i % 12;
        *(float4*)&outp[((size_t)b * NN + n0 + p) * DI + co + o4 * 4] = *(const float4*)&xs[p][o4 * 4];
    }
}

// ------- D+E1: conv+silu + x_proj + dt_proj + scan-phase-1 summary, 25-pos chunk tiles -------
__launch_bounds__(256, 3)
__global__ void k_conv_scan1(const float* __restrict__ cw, const float* __restrict__ cb,
                             const float* __restrict__ xpw, const float* __restrict__ dpw,
                             const float* __restrict__ dpb, const float* __restrict__ alog,
                             const float* __restrict__ xcin,
                             float* __restrict__ xcvout, float* __restrict__ dtout,
                             float* __restrict__ bmout, float* __restrict__ cmout,
                             float* __restrict__ ca, float* __restrict__ cbv) {
    __shared__ float xcv[LCH][196];            // 19.6 KB
    __shared__ float dts[LCH][DI];             // 18.75 KB
    __shared__ float bc[LCH][33];              // bm: [0..15], cm: [16..31]
    __shared__ float dtrT[DTRK][28];
    __shared__ float cwT[4][DI];
    __shared__ float dpwT[DTRK][DI];
    __shared__ float cbl[DI], dpbl[DI];
    int b = blockIdx.y, kc = blockIdx.x, n0 = kc * LCH, t = threadIdx.x;
    int l = t & 63, w = t >> 6;

    if (t < DI) {
        cbl[t] = cb[t];
        dpbl[t] = dpb[t];
        #pragma unroll
        for (int k = 0; k < 4; ++k) cwT[k][t] = cw[t * 4 + k];
        #pragma unroll
        for (int r = 0; r < DTRK; ++r) dpwT[r][t] = dpw[t * DTRK + r];
    }
    __syncthreads();

    // conv + silu
    for (int idx = t; idx < LCH * DI; idx += 256) {
        int pp = idx / DI, d = idx - pp * DI;
        float s = cbl[d];
        #pragma unroll
        for (int k = 0; k < 4; ++k) {
            int n = n0 + pp - 3 + k;
            float xv = (n >= 0) ? xcin[((size_t)b * NN + n) * DI + d] : 0.f;
            s = fmaf(cwT[k][d], xv, s);
        }
        s = s * __builtin_amdgcn_rcpf(1.f + __expf(-s));
        xcv[pp][d] = s;
        xcvout[((size_t)b * NN + n0 + pp) * DI + d] = s;
    }
    __syncthreads();

    // x_proj: lane = (p = l%32 clamped, kh = l/32 K-half); wave w -> e = w+4j
    {
        int p = (l & 31) < 25 ? (l & 31) : 24;
        int kh = l >> 5;
        float acc[10];
        #pragma unroll
        for (int j = 0; j < 10; ++j) acc[j] = 0.f;
        #pragma unroll
        for (int ci = 0; ci < 24; ++ci) {
            int c4 = kh * 24 + ci;
            float4 xv = *(const float4*)&xcv[p][c4 * 4];
            #pragma unroll
            for (int j = 0; j < 10; ++j) {
                int e = w + 4 * j;
                if (e < 38) {
                    float4 w4 = *(const float4*)&xpw[(size_t)e * DI + c4 * 4];
                    acc[j] = fmaf(xv.x, w4.x, fmaf(xv.y, w4.y, fmaf(xv.z, w4.z, fmaf(xv.w, w4.w, acc[j]))));
                }
            }
        }
        #pragma unroll
        for (int j = 0; j < 10; ++j) acc[j] += __shfl_xor(acc[j], 32);
        if ((l & 31) < 25 && l < 32) {
            #pragma unroll
            for (int j = 0; j < 10; ++j) {
                int e = w + 4 * j;
                if (e < DTRK) dtrT[e][p] = acc[j];
                else if (e < 38) bc[p][e - DTRK] = acc[j];
            }
        }
    }
    __syncthreads();

    // Bm/Cm coalesced global writes
    for (int idx = t; idx < LCH * DS; idx += 256) {
        int pp = idx / DS, si = idx % DS;
        int n = b * NN + n0 + pp;
        bmout[(size_t)n * DS + si] = bc[pp][si];
        cmout[(size_t)n * DS + si] = bc[pp][DS + si];
    }

    // dt_proj + softplus -> dts LDS + global
    for (int idx = t; idx < LCH * DI; idx += 256) {
        int pp = idx / DI, d = idx - pp * DI;
        float v = dpbl[d];
        #pragma unroll
        for (int r = 0; r < DTRK; ++r) v = fmaf(dpwT[r][d], dtrT[r][pp], v);
        v = (v > 20.f) ? v : __logf(1.f + __expf(v));
        dts[pp][d] = v;
        dtout[((size_t)b * NN + n0 + pp) * DI + d] = v;
    }
    __syncthreads();

    // scan phase 1: 3072 states, 12 per thread (u = t + k*256; d = u>>4, s = u&15)
    {
        float a_[12], ap[12], hb[12];
        #pragma unroll
        for (int k = 0; k < 12; ++k) {
            a_[k] = -expf(alog[t + k * 256]);
            ap[k] = 1.f; hb[k] = 0.f;
        }
        int s_ = t & 15;
        for (int i = 0; i < LCH; ++i) {
            float bmv = bc[i][s_];
            #pragma unroll
            for (int k = 0; k < 12; ++k) {
                int d = (t + k * 256) >> 4;
                float dtv = dts[i][d];
                float xv  = xcv[i][d];
                float dA = __expf(dtv * a_[k]);
                ap[k] *= dA;
                hb[k] = fmaf(dA, hb[k], dtv * xv * bmv);
            }
        }
        size_t cbase = ((size_t)(b * KCH + kc)) * (DI * DS);
        #pragma unroll
        for (int k = 0; k < 12; ++k) {
            ca [cbase + t + k * 256] = ap[k];
            cbv[cbase + t + k * 256] = hb[k];
        }
    }
}

// ------- F: scan phase 2 — sequential over chunks, 8-deep pipelined -------
__global__ void k_scan2(const float* __restrict__ ca, const float* __restrict__ cbv,
                        float* __restrict__ hs) {
    int tid = blockIdx.x * 64 + threadIdx.x; // 6144 total
    int b = tid / (DI * DS), ds_ = tid % (DI * DS);
    size_t base = (size_t)b * KCH * (DI * DS) + ds_;
    float h = 0.f;
    for (int kc = 0; kc < KCH; kc += 8) {
        float av[8], bv[8];
        #pragma unroll
        for (int u = 0; u < 8; ++u) {
            size_t idx = base + (size_t)(kc + u) * (DI * DS);
            av[u] = ca[idx];
            bv[u] = cbv[idx];
        }
        #pragma unroll
        for (int u = 0; u < 8; ++u) {
            hs[base + (size_t)(kc + u) * (DI * DS)] = h;
            h = fmaf(av[u], h, bv[u]);
        }
    }
}

// ------- G: scan phase 3 — replay + y + gate; 8 states/lane, 1 shfl/step -------
__launch_bounds__(256)
__global__ void k_scan3(const float* __restrict__ alog, const float* __restrict__ Dp,
                        const float* __restrict__ dt, const float* __restrict__ xcv,
                        const float* __restrict__ bm, const float* __restrict__ cm,
                        const float* __restrict__ zin, const float* __restrict__ hs,
                        float* __restrict__ yout) {
    int t = threadIdx.x, w = t >> 6, l = t & 63;
    int T = blockIdx.x * 4 + w;
    int b = T / (KCH * 6), rem = T % (KCH * 6);
    int kc = rem / 6, dg = rem % 6;
    int dl = l & 31, sh = l >> 5;
    int d = dg * 32 + dl;
    float a[8];
    #pragma unroll
    for (int j = 0; j < 8; ++j) a[j] = -expf(alog[d * DS + sh * 8 + j]);
    float dpar = Dp[d];
    size_t nbase = (size_t)b * NN + kc * LCH;
    size_t cidx = ((size_t)(b * KCH + kc) * DI + d) * DS + sh * 8;
    float h[8];
    {
        float4 h0 = *(const float4*)&hs[cidx];
        float4 h1 = *(const float4*)&hs[cidx + 4];
        h[0]=h0.x; h[1]=h0.y; h[2]=h0.z; h[3]=h0.w;
        h[4]=h1.x; h[5]=h1.y; h[6]=h1.z; h[7]=h1.w;
    }
    for (int i = 0; i < LCH; ++i) {
        size_t g = (nbase + i) * DI + d;
        float dtv = dt[g];
        float xv  = xcv[g];
        float zv  = zin[g];
        size_t sb = (nbase + i) * DS + sh * 8;
        const float4* b4 = (const float4*)&bm[sb];
        const float4* c4p = (const float4*)&cm[sb];
        float4 b0 = b4[0], b1 = b4[1];
        float4 c0 = c4p[0], c1 = c4p[1];
        float bmv[8] = {b0.x,b0.y,b0.z,b0.w,b1.x,b1.y,b1.z,b1.w};
        float cmv[8] = {c0.x,c0.y,c0.z,c0.w,c1.x,c1.y,c1.z,c1.w};
        float bx_ = dtv * xv;
        float py = 0.f;
        #pragma unroll
        for (int j = 0; j < 8; ++j) {
            float dA = __expf(dtv * a[j]);
            h[j] = fmaf(dA, h[j], bx_ * bmv[j]);
            py = fmaf(h[j], cmv[j], py);
        }
        py += __shfl_xor(py, 32);
        if (l < 32) {
            float y = py + dpar * xv;
            y *= zv / (1.f + __expf(-zv));
            yout[g] = y;
        }
    }
}

// ------- H: out_proj (192 -> 96), row-major LDS, 8pos x 4out x 4 K-split -------
__launch_bounds__(256, 2)
__global__ void k_outproj(const float* __restrict__ ow, const float* __restrict__ yin,
                          float* __restrict__ yp) {
    __shared__ float wsm[32][196];
    __shared__ float yt[64][196];
    int b = blockIdx.z, g = blockIdx.y, n0 = blockIdx.x * 64, t = threadIdx.x;

    for (int i = t; i < 32 * 48; i += 256) {
        int r = i / 48, c4 = i % 48;
        *(float4*)&wsm[r][c4 * 4] = *(const float4*)(ow + (size_t)(g * 32 + r) * DI + c4 * 4);
    }
    for (int i = t; i < 64 * 48; i += 256) {
        int p = i / 48, c4 = i % 48;
        *(float4*)&yt[p][c4 * 4] = *(const float4*)(yin + ((size_t)b * NN + n0 + p) * DI + c4 * 4);
    }
    __syncthreads();

    int l = t & 63, w = t >> 6;
    int oi = l & 7;
    int kq = (l >> 3) & 3;
    int pi = w * 2 + (l >> 5);
    float acc[4][8];
    #pragma unroll
    for (int j = 0; j < 4; ++j)
        #pragma unroll
        for (int pp = 0; pp < 8; ++pp) acc[j][pp] = 0.f;

    for (int c4 = 0; c4 < 12; ++c4) {
        int cg2 = kq * 12 + c4;
        float4 b0 = *(const float4*)&wsm[oi * 4 + 0][cg2 * 4];
        float4 b1 = *(const float4*)&wsm[oi * 4 + 1][cg2 * 4];
        float4 b2 = *(const float4*)&wsm[oi * 4 + 2][cg2 * 4];
        float4 b3 = *(const float4*)&wsm[oi * 4 + 3][cg2 * 4];
        #pragma unroll
        for (int pp = 0; pp < 8; ++pp) {
            float4 a = *(const float4*)&yt[pi * 8 + pp][cg2 * 4];
            acc[0][pp] = fmaf(a.x, b0.x, fmaf(a.y, b0.y, fmaf(a.z, b0.z, fmaf(a.w, b0.w, acc[0][pp]))));
            acc[1][pp] = fmaf(a.x, b1.x, fmaf(a.y, b1.y, fmaf(a.z, b1.z, fmaf(a.w, b1.w, acc[1][pp]))));
            acc[2][pp] = fmaf(a.x, b2.x, fmaf(a.y, b2.y, fmaf(a.z, b2.z, fmaf(a.w, b2.w, acc[2][pp]))));
            acc[3][pp] = fmaf(a.x, b3.x, fmaf(a.y, b3.y, fmaf(a.z, b3.z, fmaf(a.w, b3.w, acc[3][pp]))));
        }
    }
    #pragma unroll
    for (int j = 0; j < 4; ++j)
        #pragma unroll
        for (int pp = 0; pp < 8; ++pp) {
            acc[j][pp] += __shfl_xor(acc[j][pp], 8);
            acc[j][pp] += __shfl_xor(acc[j][pp], 16);
        }
    if (kq == 0) {
        #pragma unroll
        for (int pp = 0; pp < 8; ++pp) {
            float4 v = make_float4(acc[0][pp], acc[1][pp], acc[2][pp], acc[3][pp]);
            *(float4*)&yp[((size_t)b * NN + n0 + pi * 8 + pp) * NC + g * 32 + oi * 4] = v;
        }
    }
}

// ---------------- I: gather rows by rank + transpose + coalesced final write ----------------
__launch_bounds__(256)
__global__ void k_final(const float* __restrict__ yp, const int* __restrict__ rp,
                        float* __restrict__ out) {
    __shared__ float ft[64][97];
    __shared__ int rk[64];
    int b = blockIdx.y, i0 = blockIdx.x * 64, t = threadIdx.x;
    if (t < 64) {
        int s = 0;
        #pragma unroll
        for (int c = 0; c < 8; ++c) s += rp[c * 8000 + i0 + t];
        rk[t] = s;
    }
    __syncthreads();
    for (int idx = t; idx < 64 * 24; idx += 256) {
        int ii = idx / 24, j = idx % 24;
        float4 v = *(const float4*)&yp[((size_t)b * NN + rk[ii]) * NC + j * 4];
        ft[ii][j * 4 + 0] = v.x; ft[ii][j * 4 + 1] = v.y;
        ft[ii][j * 4 + 2] = v.z; ft[ii][j * 4 + 3] = v.w;
    }
    __syncthreads();
    for (int idx = t; idx < 96 * 64; idx += 256) {
        int c = idx >> 6, ii = idx & 63;
        out[((size_t)b * NC + c) * NN + i0 + ii] = ft[ii][c];
    }
}

extern "C" void kernel_launch(void* const* d_in, const int* in_sizes, int n_in,
                              void* d_out, int out_size, void* d_ws, size_t ws_size,
                              hipStream_t stream) {
    const float* x    = (const float*)d_in[0];
    const float* pv   = (const float*)d_in[1];
    const float* nw   = (const float*)d_in[2];
    const float* nbp  = (const float*)d_in[3];
    const float* win  = (const float*)d_in[4];
    const float* cw   = (const float*)d_in[5];
    const float* cb   = (const float*)d_in[6];
    const float* xpw  = (const float*)d_in[7];
    const float* dpw  = (const float*)d_in[8];
    const float* dpb  = (const float*)d_in[9];
    const float* alog = (const float*)d_in[10];
    const float* Dp   = (const float*)d_in[11];
    const float* ow   = (const float*)d_in[12];
    float* out = (float*)d_out;
    float* ws  = (float*)d_ws;

    int*   rp   = (int*)ws + OFF_RP;
    float* xn   = ws + OFF_XN;
    float* xc   = ws + OFF_XC;
    float* z    = ws + OFF_Z;
    float* xcv  = ws + OFF_XCV;
    float* dt   = ws + OFF_DT;
    float* bmb  = ws + OFF_BM;
    float* cmb  = ws + OFF_CM;
    float* ca   = ws + OFF_CA;
    float* cbv  = ws + OFF_CB;
    float* hs   = ws + OFF_HS;
    float* y    = ws + OFF_Y;
    float* yp   = ws + OFF_YP;

    k_rank<<<dim3(32, 8), 256, 0, stream>>>(pv, rp);
    k_ln<<<dim3(125, 2), 256, 0, stream>>>(x, nw, nbp, rp, xn);
    k_inproj<<<dim3(125, 8, 2), 256, 0, stream>>>(xn, win, xc, z);
    k_conv_scan1<<<dim3(KCH, 2), 256, 0, stream>>>(cw, cb, xpw, dpw, dpb, alog, xc,
                                                   xcv, dt, bmb, cmb, ca, cbv);
    k_scan2<<<96, 64, 0, stream>>>(ca, cbv, hs);
    k_scan3<<<(NB * KCH * 6) / 4, 256, 0, stream>>>(alog, Dp, dt, xcv, bmb, cmb, z, hs, y);
    k_outproj<<<dim3(125, 3, 2), 256, 0, stream>>>(ow, y, yp);
    k_final<<<dim3(125, 2), 256, 0, stream>>>(yp, rp, out);
}

// Round 15
// 188.898 us; speedup vs baseline: 1.0375x; 1.0375x over previous
//
#include <hip/hip_runtime.h>
#include <math.h>

#define NB 2
#define NC 96
#define NN 8000
#define DI 192
#define DS 16
#define DTRK 6
#define KCH 400
#define LCH 20

// ws layout (element offsets, 4B each) — all dedicated, no aliasing
#define OFF_RP   0                              // 8*8000 int partial ranks
#define OFF_XN   64000
#define OFF_XC   (OFF_XN + NB*NN*NC)
#define OFF_Z    (OFF_XC + NB*NN*DI)
#define OFF_XCV  (OFF_Z  + NB*NN*DI)
#define OFF_DT   (OFF_XCV + NB*NN*DI)
#define OFF_BM   (OFF_DT + NB*NN*DI)
#define OFF_CM   (OFF_BM + NB*NN*DS)
#define OFF_CA   (OFF_CM + NB*NN*DS)
#define OFF_CB   (OFF_CA + NB*KCH*DI*DS)
#define OFF_HS   (OFF_CB + NB*KCH*DI*DS)
#define OFF_Y    (OFF_HS + NB*KCH*DI*DS)
#define OFF_YP   (OFF_Y  + NB*NN*DI)

// ---------------- A: O(N^2) stable rank partials; keys computed in-block ----------------
__global__ void k_rank(const float* __restrict__ pv, int* __restrict__ rp) {
    __shared__ float kj[1000];
    int t = threadIdx.x;
    float p0 = pv[0], p1 = pv[1], p2 = pv[2];
    int j0 = blockIdx.y * 1000;
    for (int j = t; j < 1000; j += 256) {
        int idx = j0 + j;
        int zz = idx / 400, rem = idx % 400, yy = rem / 20, xx = rem % 20;
        kj[j] = (float)zz * p0 + (float)yy * p1 + (float)xx * p2;
    }
    __syncthreads();
    int i = blockIdx.x * 256 + t;
    if (i >= NN) return;
    {
        int zz = i / 400, rem = i % 400, yy = rem / 20, xx = rem % 20;
        float ki = (float)zz * p0 + (float)yy * p1 + (float)xx * p2;
        int cnt = 0;
        #pragma unroll 4
        for (int j = 0; j < 1000; ++j) {
            float kv = kj[j];
            int jj = j0 + j;
            cnt += (kv < ki || (kv == ki && jj < i)) ? 1 : 0;
        }
        rp[blockIdx.y * 8000 + i] = cnt;
    }
}

// ------- B1: LayerNorm + row-scatter to sorted xn (B,N,96) -------
__launch_bounds__(256)
__global__ void k_ln(const float* __restrict__ x, const float* __restrict__ nw,
                     const float* __restrict__ nbp, const int* __restrict__ rp,
                     float* __restrict__ xn) {
    __shared__ float xt[64][100];
    __shared__ int rk[64];
    __shared__ float nwb[NC], nbb[NC];
    int b = blockIdx.y, n0 = blockIdx.x * 64, t = threadIdx.x;
    int lane = t & 63, w = t >> 6;
    if (t < 64) {
        int s = 0;
        #pragma unroll
        for (int c = 0; c < 8; ++c) s += rp[c * 8000 + n0 + t];
        rk[t] = s;
    } else if (t >= 64 && t < 160) { int c = t - 64; nwb[c] = nw[c]; nbb[c] = nbp[c]; }
    for (int idx = t; idx < NC * 64; idx += 256) {
        int c = idx >> 6, p = idx & 63;
        xt[p][c] = x[((size_t)b * NC + c) * NN + n0 + p];
    }
    __syncthreads();
    // per-lane LN (4 waves redundant)
    float xr[96];
    float s = 0.f, sq = 0.f;
    #pragma unroll
    for (int c4 = 0; c4 < 24; ++c4) {
        float4 v = *(const float4*)&xt[lane][c4 * 4];
        xr[c4*4+0] = v.x; xr[c4*4+1] = v.y; xr[c4*4+2] = v.z; xr[c4*4+3] = v.w;
        s += v.x + v.y + v.z + v.w;
        sq += v.x*v.x + v.y*v.y + v.z*v.z + v.w*v.w;
    }
    float mu = s * (1.f / 96.f);
    float var = sq * (1.f / 96.f) - mu * mu;
    float rs = rsqrtf(var + 1e-5f);
    #pragma unroll
    for (int c = 0; c < 96; ++c) xr[c] = (xr[c] - mu) * rs * nwb[c] + nbb[c];
    __syncthreads();
    if (w == 0) {
        #pragma unroll
        for (int c = 0; c < 96; ++c) xt[lane][c] = xr[c];
    }
    __syncthreads();
    for (int idx = t; idx < 64 * 24; idx += 256) {
        int p = idx / 24, c4 = idx % 24;
        *(float4*)&xn[((size_t)b * NN + rk[p]) * NC + c4 * 4] = *(const float4*)&xt[p][c4 * 4];
    }
}

// ------- B2: in_proj GEMM, row-major LDS tiles, 4pos x 3out threads -------
__launch_bounds__(256, 3)
__global__ void k_inproj(const float* __restrict__ xn, const float* __restrict__ win,
                         float* __restrict__ xcout, float* __restrict__ zout) {
    __shared__ float wsm[48][100];
    __shared__ float xs[64][100];
    int b = blockIdx.z, g = blockIdx.y, n0 = blockIdx.x * 64, t = threadIdx.x;

    for (int i = t; i < 48 * 24; i += 256) {
        int r = i / 24, c4 = i % 24;
        *(float4*)&wsm[r][c4 * 4] = *(const float4*)(win + (size_t)(g * 48 + r) * NC + c4 * 4);
    }
    for (int i = t; i < 64 * 24; i += 256) {
        int p = i / 24, c4 = i % 24;
        *(float4*)&xs[p][c4 * 4] = *(const float4*)(xn + ((size_t)b * NN + n0 + p) * NC + c4 * 4);
    }
    __syncthreads();

    int oi = t & 15, pi = t >> 4;
    float acc[3][4];
    #pragma unroll
    for (int j = 0; j < 3; ++j)
        #pragma unroll
        for (int pp = 0; pp < 4; ++pp) acc[j][pp] = 0.f;

    for (int c4 = 0; c4 < 24; ++c4) {
        float4 b0 = *(const float4*)&wsm[oi * 3 + 0][c4 * 4];
        float4 b1 = *(const float4*)&wsm[oi * 3 + 1][c4 * 4];
        float4 b2 = *(const float4*)&wsm[oi * 3 + 2][c4 * 4];
        #pragma unroll
        for (int pp = 0; pp < 4; ++pp) {
            float4 a = *(const float4*)&xs[pi * 4 + pp][c4 * 4];
            acc[0][pp] = fmaf(a.x, b0.x, fmaf(a.y, b0.y, fmaf(a.z, b0.z, fmaf(a.w, b0.w, acc[0][pp]))));
            acc[1][pp] = fmaf(a.x, b1.x, fmaf(a.y, b1.y, fmaf(a.z, b1.z, fmaf(a.w, b1.w, acc[1][pp]))));
            acc[2][pp] = fmaf(a.x, b2.x, fmaf(a.y, b2.y, fmaf(a.z, b2.z, fmaf(a.w, b2.w, acc[2][pp]))));
        }
    }
    __syncthreads();
    #pragma unroll
    for (int j = 0; j < 3; ++j)
        #pragma unroll
        for (int pp = 0; pp < 4; ++pp) xs[pi * 4 + pp][oi * 3 + j] = acc[j][pp];
    __syncthreads();

    float* outp = (g < 4) ? xcout : zout;
    int co = (g & 3) * 48;
    for (int i = t; i < 64 * 12; i += 256) {
        int p = i / 12, o4 = i % 12;
        *(float4*)&outp[((size_t)b * NN + n0 + p) * DI + co + o4 * 4] = *(const float4*)&xs[p][o4 * 4];
    }
}

// ------- D: conv+silu + x_proj + dt_proj, 8-pos tiles, staged weights, fast math -------
__launch_bounds__(256, 8)
__global__ void k_conv_xdt(const float* __restrict__ cw, const float* __restrict__ cb,
                           const float* __restrict__ xpw, const float* __restrict__ dpw,
                           const float* __restrict__ dpb, const float* __restrict__ xcin,
                           float* __restrict__ xcvout, float* __restrict__ dtout,
                           float* __restrict__ bmout, float* __restrict__ cmout) {
    __shared__ float xcv[8][196];
    __shared__ float dtrT[DTRK][9];
    __shared__ float bc[8][33];
    __shared__ float cwT[4][DI];
    __shared__ float dpwT[DTRK][DI];
    __shared__ float cbl[DI], dpbl[DI];
    int b = blockIdx.y, n0 = blockIdx.x * 8, t = threadIdx.x;
    int l = t & 63, w = t >> 6;
    int p = l & 7, q = l >> 3;

    if (t < DI) {
        cbl[t] = cb[t];
        dpbl[t] = dpb[t];
        #pragma unroll
        for (int k = 0; k < 4; ++k) cwT[k][t] = cw[t * 4 + k];
        #pragma unroll
        for (int r = 0; r < DTRK; ++r) dpwT[r][t] = dpw[t * DTRK + r];
    }
    __syncthreads();

    {
        int pp = t / DI, d = t - pp * DI;
        #pragma unroll
        for (int i = 0; i < 6; ++i) {
            float s = cbl[d];
            #pragma unroll
            for (int k = 0; k < 4; ++k) {
                int n = n0 + pp - 3 + k;
                float xv = (n >= 0) ? xcin[((size_t)b * NN + n) * DI + d] : 0.f;
                s = fmaf(cwT[k][d], xv, s);
            }
            s = s * __builtin_amdgcn_rcpf(1.f + __expf(-s));
            xcv[pp][d] = s;
            xcvout[((size_t)b * NN + n0 + pp) * DI + d] = s;
            pp += 1; d += 64;
            if (d >= DI) { d -= DI; pp += 1; }
        }
    }
    __syncthreads();

    float acc[10];
    #pragma unroll
    for (int j = 0; j < 10; ++j) acc[j] = 0.f;
    #pragma unroll
    for (int ci = 0; ci < 6; ++ci) {
        int c4 = q * 6 + ci;
        float4 xv = *(const float4*)&xcv[p][c4 * 4];
        #pragma unroll
        for (int j = 0; j < 10; ++j) {
            int e = w + 4 * j;
            if (e < 38) {
                float4 w4 = *(const float4*)&xpw[(size_t)e * DI + c4 * 4];
                acc[j] = fmaf(xv.x, w4.x, fmaf(xv.y, w4.y, fmaf(xv.z, w4.z, fmaf(xv.w, w4.w, acc[j]))));
            }
        }
    }
    #pragma unroll
    for (int j = 0; j < 10; ++j) {
        acc[j] += __shfl_xor(acc[j], 8);
        acc[j] += __shfl_xor(acc[j], 16);
        acc[j] += __shfl_xor(acc[j], 32);
    }
    if (l < 8) {
        #pragma unroll
        for (int j = 0; j < 10; ++j) {
            int e = w + 4 * j;
            if (e < DTRK) dtrT[e][p] = acc[j];
            else if (e < 38) bc[p][e - DTRK] = acc[j];
        }
    }
    __syncthreads();

    if (t < 8 * DS) {
        int pp = t >> 4, si = t & 15;
        int n = b * NN + n0 + pp;
        bmout[(size_t)n * DS + si] = bc[pp][si];
        cmout[(size_t)n * DS + si] = bc[pp][DS + si];
    }

    float dv[6];
    {
        int d0 = q * 24 + w * 6;
        #pragma unroll
        for (int jd = 0; jd < 6; ++jd) {
            int d = d0 + jd;
            float v = dpbl[d];
            #pragma unroll
            for (int r = 0; r < DTRK; ++r) v = fmaf(dpwT[r][d], dtrT[r][p], v);
            v = (v > 20.f) ? v : __logf(1.f + __expf(v));
            dv[jd] = v;
        }
    }
    __syncthreads();
    {
        int d0 = q * 24 + w * 6;
        #pragma unroll
        for (int jd = 0; jd < 6; ++jd) xcv[p][d0 + jd] = dv[jd];
    }
    __syncthreads();
    for (int idx = t; idx < 8 * 48; idx += 256) {
        int pp = idx / 48, o4 = idx % 48;
        *(float4*)&dtout[((size_t)b * NN + n0 + pp) * DI + o4 * 4] = *(const float4*)&xcv[pp][o4 * 4];
    }
}

// ------- E: scan phase 1 — lane owns 8 states of one d; direct coalesced loads -------
__launch_bounds__(256)
__global__ void k_scan1(const float* __restrict__ alog, const float* __restrict__ dt,
                        const float* __restrict__ xcv, const float* __restrict__ bm,
                        float* __restrict__ ca, float* __restrict__ cbv) {
    int t = threadIdx.x, w = t >> 6, l = t & 63;
    int T = blockIdx.x * 4 + w;                 // 4800 wave-tasks
    int b = T / (KCH * 6), rem = T % (KCH * 6);
    int kc = rem / 6, dg = rem % 6;
    int dl = l & 31, sh = l >> 5;
    int d = dg * 32 + dl;
    float a[8];
    #pragma unroll
    for (int j = 0; j < 8; ++j) a[j] = -expf(alog[d * DS + sh * 8 + j]);
    size_t nbase = (size_t)b * NN + kc * LCH;
    float ap[8], hb[8];
    #pragma unroll
    for (int j = 0; j < 8; ++j) { ap[j] = 1.f; hb[j] = 0.f; }
    for (int i = 0; i < LCH; ++i) {
        size_t g = (nbase + i) * DI + d;
        float dtv = dt[g];
        float xv  = xcv[g];
        const float4* b4 = (const float4*)&bm[(nbase + i) * DS + sh * 8];
        float4 b0 = b4[0], b1 = b4[1];
        float bmv[8] = {b0.x,b0.y,b0.z,b0.w,b1.x,b1.y,b1.z,b1.w};
        float bx_ = dtv * xv;
        #pragma unroll
        for (int j = 0; j < 8; ++j) {
            float dA = __expf(dtv * a[j]);
            ap[j] *= dA;
            hb[j] = fmaf(dA, hb[j], bx_ * bmv[j]);
        }
    }
    size_t cidx = ((size_t)(b * KCH + kc) * DI + d) * DS + sh * 8;
    *(float4*)&ca[cidx]      = make_float4(ap[0],ap[1],ap[2],ap[3]);
    *(float4*)&ca[cidx + 4]  = make_float4(ap[4],ap[5],ap[6],ap[7]);
    *(float4*)&cbv[cidx]     = make_float4(hb[0],hb[1],hb[2],hb[3]);
    *(float4*)&cbv[cidx + 4] = make_float4(hb[4],hb[5],hb[6],hb[7]);
}

// ------- F: scan phase 2 — sequential over chunks, 8-deep pipelined -------
__global__ void k_scan2(const float* __restrict__ ca, const float* __restrict__ cbv,
                        float* __restrict__ hs) {
    int tid = blockIdx.x * 64 + threadIdx.x; // 6144 total
    int b = tid / (DI * DS), ds_ = tid % (DI * DS);
    size_t base = (size_t)b * KCH * (DI * DS) + ds_;
    float h = 0.f;
    for (int kc = 0; kc < KCH; kc += 8) {
        float av[8], bv[8];
        #pragma unroll
        for (int u = 0; u < 8; ++u) {
            size_t idx = base + (size_t)(kc + u) * (DI * DS);
            av[u] = ca[idx];
            bv[u] = cbv[idx];
        }
        #pragma unroll
        for (int u = 0; u < 8; ++u) {
            hs[base + (size_t)(kc + u) * (DI * DS)] = h;
            h = fmaf(av[u], h, bv[u]);
        }
    }
}

// ------- G: scan phase 3 — replay + y + gate; 8 states/lane, 1 shfl/step -------
__launch_bounds__(256)
__global__ void k_scan3(const float* __restrict__ alog, const float* __restrict__ Dp,
                        const float* __restrict__ dt, const float* __restrict__ xcv,
                        const float* __restrict__ bm, const float* __restrict__ cm,
                        const float* __restrict__ zin, const float* __restrict__ hs,
                        float* __restrict__ yout) {
    int t = threadIdx.x, w = t >> 6, l = t & 63;
    int T = blockIdx.x * 4 + w;
    int b = T / (KCH * 6), rem = T % (KCH * 6);
    int kc = rem / 6, dg = rem % 6;
    int dl = l & 31, sh = l >> 5;
    int d = dg * 32 + dl;
    float a[8];
    #pragma unroll
    for (int j = 0; j < 8; ++j) a[j] = -expf(alog[d * DS + sh * 8 + j]);
    float dpar = Dp[d];
    size_t nbase = (size_t)b * NN + kc * LCH;
    size_t cidx = ((size_t)(b * KCH + kc) * DI + d) * DS + sh * 8;
    float h[8];
    {
        float4 h0 = *(const float4*)&hs[cidx];
        float4 h1 = *(const float4*)&hs[cidx + 4];
        h[0]=h0.x; h[1]=h0.y; h[2]=h0.z; h[3]=h0.w;
        h[4]=h1.x; h[5]=h1.y; h[6]=h1.z; h[7]=h1.w;
    }
    for (int i = 0; i < LCH; ++i) {
        size_t g = (nbase + i) * DI + d;
        float dtv = dt[g];
        float xv  = xcv[g];
        float zv  = zin[g];
        size_t sb = (nbase + i) * DS + sh * 8;
        const float4* b4 = (const float4*)&bm[sb];
        const float4* c4p = (const float4*)&cm[sb];
        float4 b0 = b4[0], b1 = b4[1];
        float4 c0 = c4p[0], c1 = c4p[1];
        float bmv[8] = {b0.x,b0.y,b0.z,b0.w,b1.x,b1.y,b1.z,b1.w};
        float cmv[8] = {c0.x,c0.y,c0.z,c0.w,c1.x,c1.y,c1.z,c1.w};
        float bx_ = dtv * xv;
        float py = 0.f;
        #pragma unroll
        for (int j = 0; j < 8; ++j) {
            float dA = __expf(dtv * a[j]);
            h[j] = fmaf(dA, h[j], bx_ * bmv[j]);
            py = fmaf(h[j], cmv[j], py);
        }
        py += __shfl_xor(py, 32);
        if (l < 32) {
            float y = py + dpar * xv;
            y *= zv / (1.f + __expf(-zv));
            yout[g] = y;
        }
    }
}

// ------- H: out_proj (192 -> 96), row-major LDS, 8pos x 4out x 4 K-split -------
__launch_bounds__(256, 2)
__global__ void k_outproj(const float* __restrict__ ow, const float* __restrict__ yin,
                          float* __restrict__ yp) {
    __shared__ float wsm[32][196];
    __shared__ float yt[64][196];
    int b = blockIdx.z, g = blockIdx.y, n0 = blockIdx.x * 64, t = threadIdx.x;

    for (int i = t; i < 32 * 48; i += 256) {
        int r = i / 48, c4 = i % 48;
        *(float4*)&wsm[r][c4 * 4] = *(const float4*)(ow + (size_t)(g * 32 + r) * DI + c4 * 4);
    }
    for (int i = t; i < 64 * 48; i += 256) {
        int p = i / 48, c4 = i % 48;
        *(float4*)&yt[p][c4 * 4] = *(const float4*)(yin + ((size_t)b * NN + n0 + p) * DI + c4 * 4);
    }
    __syncthreads();

    int l = t & 63, w = t >> 6;
    int oi = l & 7;
    int kq = (l >> 3) & 3;
    int pi = w * 2 + (l >> 5);
    float acc[4][8];
    #pragma unroll
    for (int j = 0; j < 4; ++j)
        #pragma unroll
        for (int pp = 0; pp < 8; ++pp) acc[j][pp] = 0.f;

    for (int c4 = 0; c4 < 12; ++c4) {
        int cg2 = kq * 12 + c4;
        float4 b0 = *(const float4*)&wsm[oi * 4 + 0][cg2 * 4];
        float4 b1 = *(const float4*)&wsm[oi * 4 + 1][cg2 * 4];
        float4 b2 = *(const float4*)&wsm[oi * 4 + 2][cg2 * 4];
        float4 b3 = *(const float4*)&wsm[oi * 4 + 3][cg2 * 4];
        #pragma unroll
        for (int pp = 0; pp < 8; ++pp) {
            float4 a = *(const float4*)&yt[pi * 8 + pp][cg2 * 4];
            acc[0][pp] = fmaf(a.x, b0.x, fmaf(a.y, b0.y, fmaf(a.z, b0.z, fmaf(a.w, b0.w, acc[0][pp]))));
            acc[1][pp] = fmaf(a.x, b1.x, fmaf(a.y, b1.y, fmaf(a.z, b1.z, fmaf(a.w, b1.w, acc[1][pp]))));
            acc[2][pp] = fmaf(a.x, b2.x, fmaf(a.y, b2.y, fmaf(a.z, b2.z, fmaf(a.w, b2.w, acc[2][pp]))));
            acc[3][pp] = fmaf(a.x, b3.x, fmaf(a.y, b3.y, fmaf(a.z, b3.z, fmaf(a.w, b3.w, acc[3][pp]))));
        }
    }
    #pragma unroll
    for (int j = 0; j < 4; ++j)
        #pragma unroll
        for (int pp = 0; pp < 8; ++pp) {
            acc[j][pp] += __shfl_xor(acc[j][pp], 8);
            acc[j][pp] += __shfl_xor(acc[j][pp], 16);
        }
    if (kq == 0) {
        #pragma unroll
        for (int pp = 0; pp < 8; ++pp) {
            float4 v = make_float4(acc[0][pp], acc[1][pp], acc[2][pp], acc[3][pp]);
            *(float4*)&yp[((size_t)b * NN + n0 + pi * 8 + pp) * NC + g * 32 + oi * 4] = v;
        }
    }
}

// ---------------- I: gather rows by rank + transpose + coalesced final write ----------------
__launch_bounds__(256)
__global__ void k_final(const float* __restrict__ yp, const int* __restrict__ rp,
                        float* __restrict__ out) {
    __shared__ float ft[64][97];
    __shared__ int rk[64];
    int b = blockIdx.y, i0 = blockIdx.x * 64, t = threadIdx.x;
    if (t < 64) {
        int s = 0;
        #pragma unroll
        for (int c = 0; c < 8; ++c) s += rp[c * 8000 + i0 + t];
        rk[t] = s;
    }
    __syncthreads();
    for (int idx = t; idx < 64 * 24; idx += 256) {
        int ii = idx / 24, j = idx % 24;
        float4 v = *(const float4*)&yp[((size_t)b * NN + rk[ii]) * NC + j * 4];
        ft[ii][j * 4 + 0] = v.x; ft[ii][j * 4 + 1] = v.y;
        ft[ii][j * 4 + 2] = v.z; ft[ii][j * 4 + 3] = v.w;
    }
    __syncthreads();
    for (int idx = t; idx < 96 * 64; idx += 256) {
        int c = idx >> 6, ii = idx & 63;
        out[((size_t)b * NC + c) * NN + i0 + ii] = ft[ii][c];
    }
}

extern "C" void kernel_launch(void* const* d_in, const int* in_sizes, int n_in,
                              void* d_out, int out_size, void* d_ws, size_t ws_size,
                              hipStream_t stream) {
    const float* x    = (const float*)d_in[0];
    const float* pv   = (const float*)d_in[1];
    const float* nw   = (const float*)d_in[2];
    const float* nbp  = (const float*)d_in[3];
    const float* win  = (const float*)d_in[4];
    const float* cw   = (const float*)d_in[5];
    const float* cb   = (const float*)d_in[6];
    const float* xpw  = (const float*)d_in[7];
    const float* dpw  = (const float*)d_in[8];
    const float* dpb  = (const float*)d_in[9];
    const float* alog = (const float*)d_in[10];
    const float* Dp   = (const float*)d_in[11];
    const float* ow   = (const float*)d_in[12];
    float* out = (float*)d_out;
    float* ws  = (float*)d_ws;

    int*   rp   = (int*)ws + OFF_RP;
    float* xn   = ws + OFF_XN;
    float* xc   = ws + OFF_XC;
    float* z    = ws + OFF_Z;
    float* xcv  = ws + OFF_XCV;
    float* dt   = ws + OFF_DT;
    float* bmb  = ws + OFF_BM;
    float* cmb  = ws + OFF_CM;
    float* ca   = ws + OFF_CA;
    float* cbv  = ws + OFF_CB;
    float* hs   = ws + OFF_HS;
    float* y    = ws + OFF_Y;
    float* yp   = ws + OFF_YP;

    k_rank<<<dim3(32, 8), 256, 0, stream>>>(pv, rp);
    k_ln<<<dim3(125, 2), 256, 0, stream>>>(x, nw, nbp, rp, xn);
    k_inproj<<<dim3(125, 8, 2), 256, 0, stream>>>(xn, win, xc, z);
    k_conv_xdt<<<dim3(1000, 2), 256, 0, stream>>>(cw, cb, xpw, dpw, dpb, xc, xcv, dt, bmb, cmb);
    k_scan1<<<(NB * KCH * 6) / 4, 256, 0, stream>>>(alog, dt, xcv, bmb, ca, cbv);
    k_scan2<<<96, 64, 0, stream>>>(ca, cbv, hs);
    k_scan3<<<(NB * KCH * 6) / 4, 256, 0, stream>>>(alog, Dp, dt, xcv, bmb, cmb, z, hs, y);
    k_outproj<<<dim3(125, 3, 2), 256, 0, stream>>>(ow, y, yp);
    k_final<<<dim3(125, 2), 256, 0, stream>>>(yp, rp, out);
}

// Round 16
// 182.833 us; speedup vs baseline: 1.0719x; 1.0332x over previous
//
#include <hip/hip_runtime.h>
#include <math.h>

#define NB 2
#define NC 96
#define NN 8000
#define DI 192
#define DS 16
#define DTRK 6
#define KCH 320
#define LCH 25

// ws layout (element offsets, 4B each) — all dedicated, no aliasing
#define OFF_RP   0                              // 8*8000 int partial ranks
#define OFF_XN   64000
#define OFF_XC   (OFF_XN + NB*NN*NC)
#define OFF_Z    (OFF_XC + NB*NN*DI)
#define OFF_XCV  (OFF_Z  + NB*NN*DI)
#define OFF_DT   (OFF_XCV + NB*NN*DI)
#define OFF_BM   (OFF_DT + NB*NN*DI)
#define OFF_CM   (OFF_BM + NB*NN*DS)
#define OFF_CA   (OFF_CM + NB*NN*DS)
#define OFF_CB   (OFF_CA + NB*KCH*DI*DS)
#define OFF_HS   (OFF_CB + NB*KCH*DI*DS)
#define OFF_Y    (OFF_HS + NB*KCH*DI*DS)
#define OFF_YP   (OFF_Y  + NB*NN*DI)

// ---------------- A: O(N^2) stable rank partials; keys computed in-block ----------------
__global__ void k_rank(const float* __restrict__ pv, int* __restrict__ rp) {
    __shared__ float kj[1000];
    int t = threadIdx.x;
    float p0 = pv[0], p1 = pv[1], p2 = pv[2];
    int j0 = blockIdx.y * 1000;
    for (int j = t; j < 1000; j += 256) {
        int idx = j0 + j;
        int zz = idx / 400, rem = idx % 400, yy = rem / 20, xx = rem % 20;
        kj[j] = (float)zz * p0 + (float)yy * p1 + (float)xx * p2;
    }
    __syncthreads();
    int i = blockIdx.x * 256 + t;
    if (i >= NN) return;
    {
        int zz = i / 400, rem = i % 400, yy = rem / 20, xx = rem % 20;
        float ki = (float)zz * p0 + (float)yy * p1 + (float)xx * p2;
        int cnt = 0;
        #pragma unroll 4
        for (int j = 0; j < 1000; ++j) {
            float kv = kj[j];
            int jj = j0 + j;
            cnt += (kv < ki || (kv == ki && jj < i)) ? 1 : 0;
        }
        rp[blockIdx.y * 8000 + i] = cnt;
    }
}

// ------- B1: LayerNorm + row-scatter to sorted xn (B,N,96) -------
__launch_bounds__(256)
__global__ void k_ln(const float* __restrict__ x, const float* __restrict__ nw,
                     const float* __restrict__ nbp, const int* __restrict__ rp,
                     float* __restrict__ xn) {
    __shared__ float xt[64][100];
    __shared__ int rk[64];
    __shared__ float nwb[NC], nbb[NC];
    int b = blockIdx.y, n0 = blockIdx.x * 64, t = threadIdx.x;
    int lane = t & 63, w = t >> 6;
    if (t < 64) {
        int s = 0;
        #pragma unroll
        for (int c = 0; c < 8; ++c) s += rp[c * 8000 + n0 + t];
        rk[t] = s;
    } else if (t >= 64 && t < 160) { int c = t - 64; nwb[c] = nw[c]; nbb[c] = nbp[c]; }
    for (int idx = t; idx < NC * 64; idx += 256) {
        int c = idx >> 6, p = idx & 63;
        xt[p][c] = x[((size_t)b * NC + c) * NN + n0 + p];
    }
    __syncthreads();
    // per-lane LN (4 waves redundant)
    float xr[96];
    float s = 0.f, sq = 0.f;
    #pragma unroll
    for (int c4 = 0; c4 < 24; ++c4) {
        float4 v = *(const float4*)&xt[lane][c4 * 4];
        xr[c4*4+0] = v.x; xr[c4*4+1] = v.y; xr[c4*4+2] = v.z; xr[c4*4+3] = v.w;
        s += v.x + v.y + v.z + v.w;
        sq += v.x*v.x + v.y*v.y + v.z*v.z + v.w*v.w;
    }
    float mu = s * (1.f / 96.f);
    float var = sq * (1.f / 96.f) - mu * mu;
    float rs = rsqrtf(var + 1e-5f);
    #pragma unroll
    for (int c = 0; c < 96; ++c) xr[c] = (xr[c] - mu) * rs * nwb[c] + nbb[c];
    __syncthreads();
    if (w == 0) {
        #pragma unroll
        for (int c = 0; c < 96; ++c) xt[lane][c] = xr[c];
    }
    __syncthreads();
    for (int idx = t; idx < 64 * 24; idx += 256) {
        int p = idx / 24, c4 = idx % 24;
        *(float4*)&xn[((size_t)b * NN + rk[p]) * NC + c4 * 4] = *(const float4*)&xt[p][c4 * 4];
    }
}

// ------- B2: in_proj GEMM, row-major LDS tiles, 4pos x 3out threads -------
__launch_bounds__(256, 3)
__global__ void k_inproj(const float* __restrict__ xn, const float* __restrict__ win,
                         float* __restrict__ xcout, float* __restrict__ zout) {
    __shared__ float wsm[48][100];
    __shared__ float xs[64][100];
    int b = blockIdx.z, g = blockIdx.y, n0 = blockIdx.x * 64, t = threadIdx.x;

    for (int i = t; i < 48 * 24; i += 256) {
        int r = i / 24, c4 = i % 24;
        *(float4*)&wsm[r][c4 * 4] = *(const float4*)(win + (size_t)(g * 48 + r) * NC + c4 * 4);
    }
    for (int i = t; i < 64 * 24; i += 256) {
        int p = i / 24, c4 = i % 24;
        *(float4*)&xs[p][c4 * 4] = *(const float4*)(xn + ((size_t)b * NN + n0 + p) * NC + c4 * 4);
    }
    __syncthreads();

    int oi = t & 15, pi = t >> 4;
    float acc[3][4];
    #pragma unroll
    for (int j = 0; j < 3; ++j)
        #pragma unroll
        for (int pp = 0; pp < 4; ++pp) acc[j][pp] = 0.f;

    for (int c4 = 0; c4 < 24; ++c4) {
        float4 b0 = *(const float4*)&wsm[oi * 3 + 0][c4 * 4];
        float4 b1 = *(const float4*)&wsm[oi * 3 + 1][c4 * 4];
        float4 b2 = *(const float4*)&wsm[oi * 3 + 2][c4 * 4];
        #pragma unroll
        for (int pp = 0; pp < 4; ++pp) {
            float4 a = *(const float4*)&xs[pi * 4 + pp][c4 * 4];
            acc[0][pp] = fmaf(a.x, b0.x, fmaf(a.y, b0.y, fmaf(a.z, b0.z, fmaf(a.w, b0.w, acc[0][pp]))));
            acc[1][pp] = fmaf(a.x, b1.x, fmaf(a.y, b1.y, fmaf(a.z, b1.z, fmaf(a.w, b1.w, acc[1][pp]))));
            acc[2][pp] = fmaf(a.x, b2.x, fmaf(a.y, b2.y, fmaf(a.z, b2.z, fmaf(a.w, b2.w, acc[2][pp]))));
        }
    }
    __syncthreads();
    #pragma unroll
    for (int j = 0; j < 3; ++j)
        #pragma unroll
        for (int pp = 0; pp < 4; ++pp) xs[pi * 4 + pp][oi * 3 + j] = acc[j][pp];
    __syncthreads();

    float* outp = (g < 4) ? xcout : zout;
    int co = (g & 3) * 48;
    for (int i = t; i < 64 * 12; i += 256) {
        int p = i / 12, o4 = i % 12;
        *(float4*)&outp[((size_t)b * NN + n0 + p) * DI + co + o4 * 4] = *(const float4*)&xs[p][o4 * 4];
    }
}

// ------- D: conv+silu + x_proj + dt_proj, 8-pos tiles, staged weights, fast math -------
__launch_bounds__(256, 8)
__global__ void k_conv_xdt(const float* __restrict__ cw, const float* __restrict__ cb,
                           const float* __restrict__ xpw, const float* __restrict__ dpw,
                           const float* __restrict__ dpb, const float* __restrict__ xcin,
                           float* __restrict__ xcvout, float* __restrict__ dtout,
                           float* __restrict__ bmout, float* __restrict__ cmout) {
    __shared__ float xcv[8][196];
    __shared__ float dtrT[DTRK][9];
    __shared__ float bc[8][33];
    __shared__ float cwT[4][DI];
    __shared__ float dpwT[DTRK][DI];
    __shared__ float cbl[DI], dpbl[DI];
    int b = blockIdx.y, n0 = blockIdx.x * 8, t = threadIdx.x;
    int l = t & 63, w = t >> 6;
    int p = l & 7, q = l >> 3;

    if (t < DI) {
        cbl[t] = cb[t];
        dpbl[t] = dpb[t];
        #pragma unroll
        for (int k = 0; k < 4; ++k) cwT[k][t] = cw[t * 4 + k];
        #pragma unroll
        for (int r = 0; r < DTRK; ++r) dpwT[r][t] = dpw[t * DTRK + r];
    }
    __syncthreads();

    {
        int pp = t / DI, d = t - pp * DI;
        #pragma unroll
        for (int i = 0; i < 6; ++i) {
            float s = cbl[d];
            #pragma unroll
            for (int k = 0; k < 4; ++k) {
                int n = n0 + pp - 3 + k;
                float xv = (n >= 0) ? xcin[((size_t)b * NN + n) * DI + d] : 0.f;
                s = fmaf(cwT[k][d], xv, s);
            }
            s = s * __builtin_amdgcn_rcpf(1.f + __expf(-s));
            xcv[pp][d] = s;
            xcvout[((size_t)b * NN + n0 + pp) * DI + d] = s;
            pp += 1; d += 64;
            if (d >= DI) { d -= DI; pp += 1; }
        }
    }
    __syncthreads();

    float acc[10];
    #pragma unroll
    for (int j = 0; j < 10; ++j) acc[j] = 0.f;
    #pragma unroll
    for (int ci = 0; ci < 6; ++ci) {
        int c4 = q * 6 + ci;
        float4 xv = *(const float4*)&xcv[p][c4 * 4];
        #pragma unroll
        for (int j = 0; j < 10; ++j) {
            int e = w + 4 * j;
            if (e < 38) {
                float4 w4 = *(const float4*)&xpw[(size_t)e * DI + c4 * 4];
                acc[j] = fmaf(xv.x, w4.x, fmaf(xv.y, w4.y, fmaf(xv.z, w4.z, fmaf(xv.w, w4.w, acc[j]))));
            }
        }
    }
    #pragma unroll
    for (int j = 0; j < 10; ++j) {
        acc[j] += __shfl_xor(acc[j], 8);
        acc[j] += __shfl_xor(acc[j], 16);
        acc[j] += __shfl_xor(acc[j], 32);
    }
    if (l < 8) {
        #pragma unroll
        for (int j = 0; j < 10; ++j) {
            int e = w + 4 * j;
            if (e < DTRK) dtrT[e][p] = acc[j];
            else if (e < 38) bc[p][e - DTRK] = acc[j];
        }
    }
    __syncthreads();

    if (t < 8 * DS) {
        int pp = t >> 4, si = t & 15;
        int n = b * NN + n0 + pp;
        bmout[(size_t)n * DS + si] = bc[pp][si];
        cmout[(size_t)n * DS + si] = bc[pp][DS + si];
    }

    float dv[6];
    {
        int d0 = q * 24 + w * 6;
        #pragma unroll
        for (int jd = 0; jd < 6; ++jd) {
            int d = d0 + jd;
            float v = dpbl[d];
            #pragma unroll
            for (int r = 0; r < DTRK; ++r) v = fmaf(dpwT[r][d], dtrT[r][p], v);
            v = (v > 20.f) ? v : __logf(1.f + __expf(v));
            dv[jd] = v;
        }
    }
    __syncthreads();
    {
        int d0 = q * 24 + w * 6;
        #pragma unroll
        for (int jd = 0; jd < 6; ++jd) xcv[p][d0 + jd] = dv[jd];
    }
    __syncthreads();
    for (int idx = t; idx < 8 * 48; idx += 256) {
        int pp = idx / 48, o4 = idx % 48;
        *(float4*)&dtout[((size_t)b * NN + n0 + pp) * DI + o4 * 4] = *(const float4*)&xcv[pp][o4 * 4];
    }
}

// ------- E: scan phase 1 — lane owns 8 states of one d; direct coalesced loads -------
__launch_bounds__(256)
__global__ void k_scan1(const float* __restrict__ alog, const float* __restrict__ dt,
                        const float* __restrict__ xcv, const float* __restrict__ bm,
                        float* __restrict__ ca, float* __restrict__ cbv) {
    int t = threadIdx.x, w = t >> 6, l = t & 63;
    int T = blockIdx.x * 4 + w;                 // 3840 wave-tasks
    int b = T / (KCH * 6), rem = T % (KCH * 6);
    int kc = rem / 6, dg = rem % 6;
    int dl = l & 31, sh = l >> 5;
    int d = dg * 32 + dl;
    float a[8];
    #pragma unroll
    for (int j = 0; j < 8; ++j) a[j] = -expf(alog[d * DS + sh * 8 + j]);
    size_t nbase = (size_t)b * NN + kc * LCH;
    float ap[8], hb[8];
    #pragma unroll
    for (int j = 0; j < 8; ++j) { ap[j] = 1.f; hb[j] = 0.f; }
    for (int i = 0; i < LCH; ++i) {
        size_t g = (nbase + i) * DI + d;
        float dtv = dt[g];
        float xv  = xcv[g];
        const float4* b4 = (const float4*)&bm[(nbase + i) * DS + sh * 8];
        float4 b0 = b4[0], b1 = b4[1];
        float bmv[8] = {b0.x,b0.y,b0.z,b0.w,b1.x,b1.y,b1.z,b1.w};
        float bx_ = dtv * xv;
        #pragma unroll
        for (int j = 0; j < 8; ++j) {
            float dA = __expf(dtv * a[j]);
            ap[j] *= dA;
            hb[j] = fmaf(dA, hb[j], bx_ * bmv[j]);
        }
    }
    size_t cidx = ((size_t)(b * KCH + kc) * DI + d) * DS + sh * 8;
    *(float4*)&ca[cidx]      = make_float4(ap[0],ap[1],ap[2],ap[3]);
    *(float4*)&ca[cidx + 4]  = make_float4(ap[4],ap[5],ap[6],ap[7]);
    *(float4*)&cbv[cidx]     = make_float4(hb[0],hb[1],hb[2],hb[3]);
    *(float4*)&cbv[cidx + 4] = make_float4(hb[4],hb[5],hb[6],hb[7]);
}

// ------- F: scan phase 2 — sequential over chunks, 8-deep pipelined -------
__global__ void k_scan2(const float* __restrict__ ca, const float* __restrict__ cbv,
                        float* __restrict__ hs) {
    int tid = blockIdx.x * 64 + threadIdx.x; // 6144 total
    int b = tid / (DI * DS), ds_ = tid % (DI * DS);
    size_t base = (size_t)b * KCH * (DI * DS) + ds_;
    float h = 0.f;
    for (int kc = 0; kc < KCH; kc += 8) {
        float av[8], bv[8];
        #pragma unroll
        for (int u = 0; u < 8; ++u) {
            size_t idx = base + (size_t)(kc + u) * (DI * DS);
            av[u] = ca[idx];
            bv[u] = cbv[idx];
        }
        #pragma unroll
        for (int u = 0; u < 8; ++u) {
            hs[base + (size_t)(kc + u) * (DI * DS)] = h;
            h = fmaf(av[u], h, bv[u]);
        }
    }
}

// ------- G: scan phase 3 — replay + y + gate; 8 states/lane, 1 shfl/step -------
__launch_bounds__(256)
__global__ void k_scan3(const float* __restrict__ alog, const float* __restrict__ Dp,
                        const float* __restrict__ dt, const float* __restrict__ xcv,
                        const float* __restrict__ bm, const float* __restrict__ cm,
                        const float* __restrict__ zin, const float* __restrict__ hs,
                        float* __restrict__ yout) {
    int t = threadIdx.x, w = t >> 6, l = t & 63;
    int T = blockIdx.x * 4 + w;
    int b = T / (KCH * 6), rem = T % (KCH * 6);
    int kc = rem / 6, dg = rem % 6;
    int dl = l & 31, sh = l >> 5;
    int d = dg * 32 + dl;
    float a[8];
    #pragma unroll
    for (int j = 0; j < 8; ++j) a[j] = -expf(alog[d * DS + sh * 8 + j]);
    float dpar = Dp[d];
    size_t nbase = (size_t)b * NN + kc * LCH;
    size_t cidx = ((size_t)(b * KCH + kc) * DI + d) * DS + sh * 8;
    float h[8];
    {
        float4 h0 = *(const float4*)&hs[cidx];
        float4 h1 = *(const float4*)&hs[cidx + 4];
        h[0]=h0.x; h[1]=h0.y; h[2]=h0.z; h[3]=h0.w;
        h[4]=h1.x; h[5]=h1.y; h[6]=h1.z; h[7]=h1.w;
    }
    for (int i = 0; i < LCH; ++i) {
        size_t g = (nbase + i) * DI + d;
        float dtv = dt[g];
        float xv  = xcv[g];
        float zv  = zin[g];
        size_t sb = (nbase + i) * DS + sh * 8;
        const float4* b4 = (const float4*)&bm[sb];
        const float4* c4p = (const float4*)&cm[sb];
        float4 b0 = b4[0], b1 = b4[1];
        float4 c0 = c4p[0], c1 = c4p[1];
        float bmv[8] = {b0.x,b0.y,b0.z,b0.w,b1.x,b1.y,b1.z,b1.w};
        float cmv[8] = {c0.x,c0.y,c0.z,c0.w,c1.x,c1.y,c1.z,c1.w};
        float bx_ = dtv * xv;
        float py = 0.f;
        #pragma unroll
        for (int j = 0; j < 8; ++j) {
            float dA = __expf(dtv * a[j]);
            h[j] = fmaf(dA, h[j], bx_ * bmv[j]);
            py = fmaf(h[j], cmv[j], py);
        }
        py += __shfl_xor(py, 32);
        if (l < 32) {
            float y = py + dpar * xv;
            y *= zv / (1.f + __expf(-zv));
            yout[g] = y;
        }
    }
}

// ------- H: out_proj (192 -> 96), row-major LDS, 8pos x 4out x 4 K-split -------
__launch_bounds__(256, 2)
__global__ void k_outproj(const float* __restrict__ ow, const float* __restrict__ yin,
                          float* __restrict__ yp) {
    __shared__ float wsm[32][196];
    __shared__ float yt[64][196];
    int b = blockIdx.z, g = blockIdx.y, n0 = blockIdx.x * 64, t = threadIdx.x;

    for (int i = t; i < 32 * 48; i += 256) {
        int r = i / 48, c4 = i % 48;
        *(float4*)&wsm[r][c4 * 4] = *(const float4*)(ow + (size_t)(g * 32 + r) * DI + c4 * 4);
    }
    for (int i = t; i < 64 * 48; i += 256) {
        int p = i / 48, c4 = i % 48;
        *(float4*)&yt[p][c4 * 4] = *(const float4*)(yin + ((size_t)b * NN + n0 + p) * DI + c4 * 4);
    }
    __syncthreads();

    int l = t & 63, w = t >> 6;
    int oi = l & 7;
    int kq = (l >> 3) & 3;
    int pi = w * 2 + (l >> 5);
    float acc[4][8];
    #pragma unroll
    for (int j = 0; j < 4; ++j)
        #pragma unroll
        for (int pp = 0; pp < 8; ++pp) acc[j][pp] = 0.f;

    for (int c4 = 0; c4 < 12; ++c4) {
        int cg2 = kq * 12 + c4;
        float4 b0 = *(const float4*)&wsm[oi * 4 + 0][cg2 * 4];
        float4 b1 = *(const float4*)&wsm[oi * 4 + 1][cg2 * 4];
        float4 b2 = *(const float4*)&wsm[oi * 4 + 2][cg2 * 4];
        float4 b3 = *(const float4*)&wsm[oi * 4 + 3][cg2 * 4];
        #pragma unroll
        for (int pp = 0; pp < 8; ++pp) {
            float4 a = *(const float4*)&yt[pi * 8 + pp][cg2 * 4];
            acc[0][pp] = fmaf(a.x, b0.x, fmaf(a.y, b0.y, fmaf(a.z, b0.z, fmaf(a.w, b0.w, acc[0][pp]))));
            acc[1][pp] = fmaf(a.x, b1.x, fmaf(a.y, b1.y, fmaf(a.z, b1.z, fmaf(a.w, b1.w, acc[1][pp]))));
            acc[2][pp] = fmaf(a.x, b2.x, fmaf(a.y, b2.y, fmaf(a.z, b2.z, fmaf(a.w, b2.w, acc[2][pp]))));
            acc[3][pp] = fmaf(a.x, b3.x, fmaf(a.y, b3.y, fmaf(a.z, b3.z, fmaf(a.w, b3.w, acc[3][pp]))));
        }
    }
    #pragma unroll
    for (int j = 0; j < 4; ++j)
        #pragma unroll
        for (int pp = 0; pp < 8; ++pp) {
            acc[j][pp] += __shfl_xor(acc[j][pp], 8);
            acc[j][pp] += __shfl_xor(acc[j][pp], 16);
        }
    if (kq == 0) {
        #pragma unroll
        for (int pp = 0; pp < 8; ++pp) {
            float4 v = make_float4(acc[0][pp], acc[1][pp], acc[2][pp], acc[3][pp]);
            *(float4*)&yp[((size_t)b * NN + n0 + pi * 8 + pp) * NC + g * 32 + oi * 4] = v;
        }
    }
}

// ---------------- I: gather rows by rank + transpose + coalesced final write ----------------
__launch_bounds__(256)
__global__ void k_final(const float* __restrict__ yp, const int* __restrict__ rp,
                        float* __restrict__ out) {
    __shared__ float ft[64][97];
    __shared__ int rk[64];
    int b = blockIdx.y, i0 = blockIdx.x * 64, t = threadIdx.x;
    if (t < 64) {
        int s = 0;
        #pragma unroll
        for (int c = 0; c < 8; ++c) s += rp[c * 8000 + i0 + t];
        rk[t] = s;
    }
    __syncthreads();
    for (int idx = t; idx < 64 * 24; idx += 256) {
        int ii = idx / 24, j = idx % 24;
        float4 v = *(const float4*)&yp[((size_t)b * NN + rk[ii]) * NC + j * 4];
        ft[ii][j * 4 + 0] = v.x; ft[ii][j * 4 + 1] = v.y;
        ft[ii][j * 4 + 2] = v.z; ft[ii][j * 4 + 3] = v.w;
    }
    __syncthreads();
    for (int idx = t; idx < 96 * 64; idx += 256) {
        int c = idx >> 6, ii = idx & 63;
        out[((size_t)b * NC + c) * NN + i0 + ii] = ft[ii][c];
    }
}

extern "C" void kernel_launch(void* const* d_in, const int* in_sizes, int n_in,
                              void* d_out, int out_size, void* d_ws, size_t ws_size,
                              hipStream_t stream) {
    const float* x    = (const float*)d_in[0];
    const float* pv   = (const float*)d_in[1];
    const float* nw   = (const float*)d_in[2];
    const float* nbp  = (const float*)d_in[3];
    const float* win  = (const float*)d_in[4];
    const float* cw   = (const float*)d_in[5];
    const float* cb   = (const float*)d_in[6];
    const float* xpw  = (const float*)d_in[7];
    const float* dpw  = (const float*)d_in[8];
    const float* dpb  = (const float*)d_in[9];
    const float* alog = (const float*)d_in[10];
    const float* Dp   = (const float*)d_in[11];
    const float* ow   = (const float*)d_in[12];
    float* out = (float*)d_out;
    float* ws  = (float*)d_ws;

    int*   rp   = (int*)ws + OFF_RP;
    float* xn   = ws + OFF_XN;
    float* xc   = ws + OFF_XC;
    float* z    = ws + OFF_Z;
    float* xcv  = ws + OFF_XCV;
    float* dt   = ws + OFF_DT;
    float* bmb  = ws + OFF_BM;
    float* cmb  = ws + OFF_CM;
    float* ca   = ws + OFF_CA;
    float* cbv  = ws + OFF_CB;
    float* hs   = ws + OFF_HS;
    float* y    = ws + OFF_Y;
    float* yp   = ws + OFF_YP;

    k_rank<<<dim3(32, 8), 256, 0, stream>>>(pv, rp);
    k_ln<<<dim3(125, 2), 256, 0, stream>>>(x, nw, nbp, rp, xn);
    k_inproj<<<dim3(125, 8, 2), 256, 0, stream>>>(xn, win, xc, z);
    k_conv_xdt<<<dim3(1000, 2), 256, 0, stream>>>(cw, cb, xpw, dpw, dpb, xc, xcv, dt, bmb, cmb);
    k_scan1<<<(NB * KCH * 6) / 4, 256, 0, stream>>>(alog, dt, xcv, bmb, ca, cbv);
    k_scan2<<<96, 64, 0, stream>>>(ca, cbv, hs);
    k_scan3<<<(NB * KCH * 6) / 4, 256, 0, stream>>>(alog, Dp, dt, xcv, bmb, cmb, z, hs, y);
    k_outproj<<<dim3(125, 3, 2), 256, 0, stream>>>(ow, y, yp);
    k_final<<<dim3(125, 2), 256, 0, stream>>>(yp, rp, out);
}